// Round 1
// 3961.611 us; speedup vs baseline: 2.4351x; 2.4351x over previous
//
#include <hip/hip_runtime.h>
#include <hip/hip_bf16.h>
#include <cstddef>

// GPT-2 small forward: B=2, T=1024, L=6, H=12, C=768, V=50257
// All heavy GEMMs: bf16 MFMA (16x16x32), fp32 accumulate, fp32 in/out.

#define B_ 2
#define T_ 1024
#define BT 2048        // B_*T_
#define C_ 768
#define C3 2304        // 3*C
#define C4 3072        // 4*C
#define H_ 12
#define HD 64
#define L_ 6
#define V_ 50257

typedef short bf16x8 __attribute__((ext_vector_type(8)));
typedef float f32x4 __attribute__((ext_vector_type(4)));

static __device__ __forceinline__ short f2bf(float f) {
    unsigned u = __float_as_uint(f);
    unsigned r = (u + 0x7fffu + ((u >> 16) & 1u)) >> 16;
    return (short)r;
}

// ---------------------------------------------------------------- embed ----
__global__ __launch_bounds__(256) void embed_k(const int* __restrict__ idx,
                                               const float* __restrict__ emb,
                                               const float* __restrict__ pos,
                                               float* __restrict__ x) {
    int i = blockIdx.x * 256 + threadIdx.x;       // exact grid: BT*C_/256
    int bt = i / C_;
    int c = i - bt * C_;
    int t = bt & (T_ - 1);
    x[i] = emb[(size_t)idx[bt] * C_ + c] + pos[(size_t)t * C_ + c];
}

// ------------------------------------------------------------- layernorm ---
__global__ __launch_bounds__(256) void ln_k(const float* __restrict__ x,
                                            const float* __restrict__ w,
                                            const float* __restrict__ b,
                                            float* __restrict__ y) {
    int row = blockIdx.x;
    int tid = threadIdx.x;
    int lane = tid & 63, wv = tid >> 6;
    const float* xr = x + (size_t)row * C_;
    float v0 = xr[tid], v1 = xr[tid + 256], v2 = xr[tid + 512];
    float s = v0 + v1 + v2;
    #pragma unroll
    for (int off = 32; off; off >>= 1) s += __shfl_xor(s, off);
    __shared__ float wr[4];
    __shared__ float wr2[4];
    if (lane == 0) wr[wv] = s;
    __syncthreads();
    float mean = (wr[0] + wr[1] + wr[2] + wr[3]) * (1.0f / 768.0f);
    float d0 = v0 - mean, d1 = v1 - mean, d2 = v2 - mean;
    float sq = d0 * d0 + d1 * d1 + d2 * d2;
    #pragma unroll
    for (int off = 32; off; off >>= 1) sq += __shfl_xor(sq, off);
    if (lane == 0) wr2[wv] = sq;
    __syncthreads();
    float var = (wr2[0] + wr2[1] + wr2[2] + wr2[3]) * (1.0f / 768.0f);
    float rstd = rsqrtf(var + 1e-5f);
    float* yr = y + (size_t)row * C_;
    yr[tid]       = d0 * rstd * w[tid]       + b[tid];
    yr[tid + 256] = d1 * rstd * w[tid + 256] + b[tid + 256];
    yr[tid + 512] = d2 * rstd * w[tid + 512] + b[tid + 512];
}

// ------------------------------------------------------------------ gemm ---
// C[M,N] = A[M,K] @ B, fp32 in/out, bf16 MFMA compute.
// BTRANS=false: Bm is [K,N] row-major. BTRANS=true: Bm is [N,K] row-major.
// EPI: 0 = none; 1 = +bias, exact GELU; 2 = +resid; 3 = +bias +resid.
#define TM 128
#define TN 128
#define BK 32
#define LDT 40   // padded LDS row (bf16 elems): 80B rows keep b128 16B-aligned

template <int EPI, bool BTRANS>
__global__ __launch_bounds__(256) void gemm_k(const float* __restrict__ A,
                                              const float* __restrict__ Bm,
                                              const float* __restrict__ bias,
                                              const float* __restrict__ resid,
                                              float* __restrict__ D,
                                              int M, int N, int K) {
    __shared__ short As[TM * LDT];
    __shared__ short Bs[TN * LDT];
    int tid = threadIdx.x;
    int lane = tid & 63;
    int wid = tid >> 6;
    int wm = wid >> 1, wn = wid & 1;
    int l15 = lane & 15;
    int quad = lane >> 4;
    int m0 = blockIdx.y * TM;
    int n0 = blockIdx.x * TN;

    f32x4 acc[4][4];
    #pragma unroll
    for (int i = 0; i < 4; i++)
        #pragma unroll
        for (int j = 0; j < 4; j++)
            acc[i][j] = (f32x4){0.f, 0.f, 0.f, 0.f};

    for (int k0 = 0; k0 < K; k0 += BK) {
        __syncthreads();
        // stage A tile: [128][32] bf16, rows contiguous
        #pragma unroll
        for (int i = 0; i < 4; i++) {
            int e4 = tid + i * 256;            // 0..1023 float4 slots
            int m = e4 >> 3;                   // 8 float4 per 32-K row
            int kc = (e4 & 7) << 2;
            const float4 v = *(const float4*)(A + (size_t)(m0 + m) * K + k0 + kc);
            short* dst = &As[m * LDT + kc];
            dst[0] = f2bf(v.x); dst[1] = f2bf(v.y);
            dst[2] = f2bf(v.z); dst[3] = f2bf(v.w);
        }
        if (BTRANS) {
            // Bm [N][K]: rows of K contiguous -> direct [n][k] staging
            #pragma unroll
            for (int i = 0; i < 4; i++) {
                int e4 = tid + i * 256;
                int n = e4 >> 3;
                int kc = (e4 & 7) << 2;
                int gn = n0 + n;
                float4 v = make_float4(0.f, 0.f, 0.f, 0.f);
                if (gn < N) v = *(const float4*)(Bm + (size_t)gn * K + k0 + kc);
                short* dst = &Bs[n * LDT + kc];
                dst[0] = f2bf(v.x); dst[1] = f2bf(v.y);
                dst[2] = f2bf(v.z); dst[3] = f2bf(v.w);
            }
        } else {
            // Bm [K][N]: transpose into [n][k] during staging
            #pragma unroll
            for (int i = 0; i < 4; i++) {
                int e4 = tid + i * 256;
                int k = e4 >> 5;                 // 32 float4 per N-row of tile
                int nc = (e4 & 31) << 2;
                const float4 v = *(const float4*)(Bm + (size_t)(k0 + k) * N + n0 + nc);
                Bs[(nc + 0) * LDT + k] = f2bf(v.x);
                Bs[(nc + 1) * LDT + k] = f2bf(v.y);
                Bs[(nc + 2) * LDT + k] = f2bf(v.z);
                Bs[(nc + 3) * LDT + k] = f2bf(v.w);
            }
        }
        __syncthreads();
        bf16x8 af[4], bfr[4];
        #pragma unroll
        for (int t = 0; t < 4; t++) {
            af[t]  = *(const bf16x8*)&As[(wm * 64 + t * 16 + l15) * LDT + quad * 8];
            bfr[t] = *(const bf16x8*)&Bs[(wn * 64 + t * 16 + l15) * LDT + quad * 8];
        }
        #pragma unroll
        for (int mt = 0; mt < 4; mt++)
            #pragma unroll
            for (int nt = 0; nt < 4; nt++)
                acc[mt][nt] = __builtin_amdgcn_mfma_f32_16x16x32_bf16(
                    af[mt], bfr[nt], acc[mt][nt], 0, 0, 0);
    }

    #pragma unroll
    for (int mt = 0; mt < 4; mt++) {
        int row = m0 + wm * 64 + mt * 16 + quad * 4;
        #pragma unroll
        for (int nt = 0; nt < 4; nt++) {
            int col = n0 + wn * 64 + nt * 16 + l15;
            if (col < N) {
                #pragma unroll
                for (int r = 0; r < 4; r++) {
                    float v = acc[mt][nt][r];
                    int rr = row + r;
                    if (EPI == 1 || EPI == 3) v += bias[col];
                    if (EPI == 1) v = 0.5f * v * (1.0f + erff(v * 0.70710678118f));
                    if (EPI == 2 || EPI == 3) v += resid[(size_t)rr * N + col];
                    D[(size_t)rr * N + col] = v;
                }
            }
        }
    }
}

// --------------------------------------------------------- flash attention -
// One block per (64-query tile, b*H). 4 waves, each owns 16 query rows.
// Per 64-key tile: stage K [j][d] and V^T [d][j] in bf16 LDS, QK^T and PV
// via mfma_f32_16x16x32_bf16, online softmax in fp32 registers.
// MFMA frag layouts (verified by gemm_k): A: lane holds A[m=lane&15][k=(lane>>4)*8..+8];
// B: lane holds Bt[n=lane&15][k=(lane>>4)*8..+8]; C/D: col=lane&15, row=(lane>>4)*4+r.
#define QBLK 64
#define KVBLK 64
#define LDK 72   // 144B rows: b128-aligned, full-BW ds_read (start banks spread)
#define LDP 72

__global__ __launch_bounds__(256) void attn_flash(const float* __restrict__ qkv,
                                                  float* __restrict__ att_out) {
    int qt = blockIdx.x;
    int bh = blockIdx.y;
    int b = bh / H_, h = bh - b * H_;
    int hoff = h * HD;
    const size_t base = (size_t)b * T_ * C3;
    int tid = threadIdx.x;
    int lane = tid & 63, w = tid >> 6;
    int l15 = lane & 15, quad = lane >> 4;

    __shared__ short Ks[KVBLK * LDK];
    __shared__ short Vs[HD * LDK];       // transposed: [d][j]
    __shared__ short Ps[4][16 * LDP];    // per-wave P re-fragment buffer

    int q0 = qt * QBLK;
    int qrow_w = q0 + w * 16;            // this wave's first query row

    // Q fragment in registers, pre-scaled by 1/sqrt(HD)=0.125 (exact pow2)
    bf16x8 qf[2];
    {
        const float* qp = qkv + base + (size_t)(qrow_w + l15) * C3 + hoff;
        #pragma unroll
        for (int ks = 0; ks < 2; ks++)
            #pragma unroll
            for (int e = 0; e < 8; e++)
                qf[ks][e] = f2bf(qp[ks * 32 + quad * 8 + e] * 0.125f);
    }

    f32x4 o[4];                          // O accum: col=nt*16+l15 (d), row=quad*4+r
    #pragma unroll
    for (int nt = 0; nt < 4; nt++) o[nt] = (f32x4){0.f, 0.f, 0.f, 0.f};
    float m_r[4] = {-1e30f, -1e30f, -1e30f, -1e30f};
    float l_r[4] = {0.f, 0.f, 0.f, 0.f};

    for (int j0 = 0; j0 < q0 + QBLK; j0 += KVBLK) {
        __syncthreads();
        // ---- stage K [64][64] row-major and V^T [64][64] into LDS (bf16) ----
        #pragma unroll
        for (int i = 0; i < 4; i++) {
            // K: coalesced float4 loads, conflict-free b64 row writes
            int e4 = tid + i * 256;
            int j = e4 >> 4;
            int dc = (e4 & 15) << 2;
            float4 kv = *(const float4*)(qkv + base + (size_t)(j0 + j) * C3 + C_ + hoff + dc);
            short4 s4 = { f2bf(kv.x), f2bf(kv.y), f2bf(kv.z), f2bf(kv.w) };
            *(short4*)&Ks[j * LDK + dc] = s4;
            // V: lane-per-j loads (4 waves cover a full 64B line per j),
            // transposed scalar writes are lane-consecutive -> conflict-free
            int jV = tid & 63;
            int dV = ((tid >> 6) + i * 4) << 2;
            float4 vv = *(const float4*)(qkv + base + (size_t)(j0 + jV) * C3 + 2 * C_ + hoff + dV);
            Vs[(dV + 0) * LDK + jV] = f2bf(vv.x);
            Vs[(dV + 1) * LDK + jV] = f2bf(vv.y);
            Vs[(dV + 2) * LDK + jV] = f2bf(vv.z);
            Vs[(dV + 3) * LDK + jV] = f2bf(vv.w);
        }
        __syncthreads();
        if (j0 > qrow_w + 15) continue;   // tile fully masked for this wave

        // ---- S = Q K^T (scaled) ----
        f32x4 s[4];
        #pragma unroll
        for (int nt = 0; nt < 4; nt++) s[nt] = (f32x4){0.f, 0.f, 0.f, 0.f};
        #pragma unroll
        for (int ks = 0; ks < 2; ks++)
            #pragma unroll
            for (int nt = 0; nt < 4; nt++) {
                bf16x8 kf = *(const bf16x8*)&Ks[(nt * 16 + l15) * LDK + ks * 32 + quad * 8];
                s[nt] = __builtin_amdgcn_mfma_f32_16x16x32_bf16(qf[ks], kf, s[nt], 0, 0, 0);
            }

        // ---- causal mask + tile row-max ----
        float tmax[4] = {-1e30f, -1e30f, -1e30f, -1e30f};
        #pragma unroll
        for (int nt = 0; nt < 4; nt++) {
            int key = j0 + nt * 16 + l15;
            #pragma unroll
            for (int r = 0; r < 4; r++) {
                int row = qrow_w + quad * 4 + r;
                if (key > row) s[nt][r] = -1e30f;
                tmax[r] = fmaxf(tmax[r], s[nt][r]);
            }
        }
        float rsum[4];
        #pragma unroll
        for (int r = 0; r < 4; r++) {
            #pragma unroll
            for (int off = 1; off < 16; off <<= 1)
                tmax[r] = fmaxf(tmax[r], __shfl_xor(tmax[r], off));
            float mnew = fmaxf(m_r[r], tmax[r]);
            float sc = __expf(m_r[r] - mnew);
            m_r[r] = mnew;
            l_r[r] *= sc;
            #pragma unroll
            for (int nt = 0; nt < 4; nt++) o[nt][r] *= sc;
            rsum[r] = 0.f;
        }

        // ---- P = exp(S - m), spill to per-wave LDS for A-frag re-layout ----
        #pragma unroll
        for (int nt = 0; nt < 4; nt++)
            #pragma unroll
            for (int r = 0; r < 4; r++) {
                float p = __expf(s[nt][r] - m_r[r]);
                rsum[r] += p;
                Ps[w][(quad * 4 + r) * LDP + nt * 16 + l15] = f2bf(p);
            }
        #pragma unroll
        for (int r = 0; r < 4; r++) {
            #pragma unroll
            for (int off = 1; off < 16; off <<= 1)
                rsum[r] += __shfl_xor(rsum[r], off);
            l_r[r] += rsum[r];
        }
        // same-wave LDS write->read: drain this wave's DS queue (lockstep wave,
        // per-wave in-order LDS; no __syncthreads needed, waves are independent)
        asm volatile("s_waitcnt lgkmcnt(0)" ::: "memory");

        // ---- O += P V ----
        #pragma unroll
        for (int ks = 0; ks < 2; ks++) {
            bf16x8 pf = *(const bf16x8*)&Ps[w][l15 * LDP + ks * 32 + quad * 8];
            #pragma unroll
            for (int nt = 0; nt < 4; nt++) {
                bf16x8 vf = *(const bf16x8*)&Vs[(nt * 16 + l15) * LDK + ks * 32 + quad * 8];
                o[nt] = __builtin_amdgcn_mfma_f32_16x16x32_bf16(pf, vf, o[nt], 0, 0, 0);
            }
        }
    }

    // ---- normalize and write out ----
    #pragma unroll
    for (int r = 0; r < 4; r++) {
        int row = qrow_w + quad * 4 + r;
        float inv = 1.0f / l_r[r];
        #pragma unroll
        for (int nt = 0; nt < 4; nt++)
            att_out[((size_t)b * T_ + row) * C_ + hoff + nt * 16 + l15] = o[nt][r] * inv;
    }
}

// ---------------------------------------------------------------- launch ---
extern "C" void kernel_launch(void* const* d_in, const int* in_sizes, int n_in,
                              void* d_out, int out_size, void* d_ws, size_t ws_size,
                              hipStream_t stream) {
    const int*   idx   = (const int*)d_in[0];
    const float* emb   = (const float*)d_in[1];
    const float* pos   = (const float*)d_in[2];
    const float* Wqkv  = (const float*)d_in[3];
    const float* Wproj = (const float*)d_in[4];
    const float* ln1w  = (const float*)d_in[5];
    const float* ln1b  = (const float*)d_in[6];
    const float* ln2w  = (const float*)d_in[7];
    const float* ln2b  = (const float*)d_in[8];
    const float* W1    = (const float*)d_in[9];
    const float* b1    = (const float*)d_in[10];
    const float* W2    = (const float*)d_in[11];
    const float* b2    = (const float*)d_in[12];
    const float* lnfw  = (const float*)d_in[13];
    const float* lnfb  = (const float*)d_in[14];
    float* out = (float*)d_out;

    float* ws   = (float*)d_ws;
    float* x    = ws;                              // BT*C
    float* lnb  = x + (size_t)BT * C_;             // BT*C
    float* qkv  = lnb + (size_t)BT * C_;           // BT*3C
    float* att  = qkv + (size_t)BT * C3;           // BT*C
    float* hbuf = att + (size_t)BT * C_;           // BT*4C

    embed_k<<<(BT * C_) / 256, 256, 0, stream>>>(idx, emb, pos, x);

    for (int l = 0; l < L_; l++) {
        ln_k<<<BT, 256, 0, stream>>>(x, ln1w + (size_t)l * C_, ln1b + (size_t)l * C_, lnb);
        gemm_k<0, false><<<dim3(C3 / TN, BT / TM), 256, 0, stream>>>(
            lnb, Wqkv + (size_t)l * C_ * C3, nullptr, nullptr, qkv, BT, C3, C_);
        attn_flash<<<dim3(T_ / QBLK, B_ * H_), 256, 0, stream>>>(qkv, att);
        gemm_k<2, false><<<dim3(C_ / TN, BT / TM), 256, 0, stream>>>(
            att, Wproj + (size_t)l * C_ * C_, nullptr, x, x, BT, C_, C_);
        ln_k<<<BT, 256, 0, stream>>>(x, ln2w + (size_t)l * C_, ln2b + (size_t)l * C_, lnb);
        gemm_k<1, false><<<dim3(C4 / TN, BT / TM), 256, 0, stream>>>(
            lnb, W1 + (size_t)l * C_ * C4, b1 + (size_t)l * C4, nullptr, hbuf, BT, C4, C_);
        gemm_k<3, false><<<dim3(C_ / TN, BT / TM), 256, 0, stream>>>(
            hbuf, W2 + (size_t)l * C4 * C_, b2 + (size_t)l * C_, x, x, BT, C_, C4);
    }

    ln_k<<<BT, 256, 0, stream>>>(x, lnfw, lnfb, lnb);
    // logits = lnb @ emb^T  (emb is [V, C] = B^T layout)
    gemm_k<0, true><<<dim3((V_ + TN - 1) / TN, BT / TM), 256, 0, stream>>>(
        lnb, emb, nullptr, nullptr, out, BT, V_, C_);
}

// Round 2
// 2326.696 us; speedup vs baseline: 4.1462x; 1.7027x over previous
//
#include <hip/hip_runtime.h>
#include <hip/hip_bf16.h>
#include <cstddef>

// GPT-2 small forward: B=2, T=1024, L=6, H=12, C=768, V=50257
// All heavy GEMMs: bf16 operands in memory, global_load_lds staging (m97
// structure: 128x128 tile, BK=32, 2-barrier loop, 16x16x32 MFMA), fp32 accum.

#define B_ 2
#define T_ 1024
#define BT 2048        // B_*T_
#define C_ 768
#define C3 2304        // 3*C
#define C4 3072        // 4*C
#define H_ 12
#define HD 64
#define L_ 6
#define V_ 50257
#define VPAD 50304     // V padded to multiple of 128 for head GEMM staging

typedef short bf16x8 __attribute__((ext_vector_type(8)));
typedef float f32x4 __attribute__((ext_vector_type(4)));
typedef unsigned short ushort_t;

static __device__ __forceinline__ short f2bf(float f) {
    unsigned u = __float_as_uint(f);
    unsigned r = (u + 0x7fffu + ((u >> 16) & 1u)) >> 16;
    return (short)r;
}

// async global->LDS, 16B per lane. dst must be wave-uniform base; HW writes
// dst + lane*16. src is per-lane.
static __device__ __forceinline__ void gload16(const ushort_t* g, ushort_t* l) {
    __builtin_amdgcn_global_load_lds(
        (const __attribute__((address_space(1))) unsigned int*)g,
        (__attribute__((address_space(3))) unsigned int*)l, 16, 0, 0);
}

// ---------------------------------------------------------------- embed ----
__global__ __launch_bounds__(256) void embed_k(const int* __restrict__ idx,
                                               const float* __restrict__ emb,
                                               const float* __restrict__ pos,
                                               float* __restrict__ x) {
    int i = blockIdx.x * 256 + threadIdx.x;       // exact grid: BT*C_/256
    int bt = i / C_;
    int c = i - bt * C_;
    int t = bt & (T_ - 1);
    x[i] = emb[(size_t)idx[bt] * C_ + c] + pos[(size_t)t * C_ + c];
}

// -------------------------------------------------- weight prep (one-time) -
// W [K][N] fp32 -> Wt [N][K] bf16, per-layer via blockIdx.z.
__global__ __launch_bounds__(256) void wconv_t(const float* __restrict__ W,
                                               ushort_t* __restrict__ Wt,
                                               int K, int N) {
    size_t loff = (size_t)blockIdx.z * K * N;
    W += loff; Wt += loff;
    __shared__ float tile[64][65];
    int t = threadIdx.x;
    int k0 = blockIdx.y * 64, n0 = blockIdx.x * 64;
    #pragma unroll
    for (int i = 0; i < 4; i++) {
        int e = t + i * 256;             // 1024 float4 slots
        int r = e >> 4;
        int c = (e & 15) * 4;
        float4 v = *(const float4*)(W + (size_t)(k0 + r) * N + n0 + c);
        tile[r][c] = v.x; tile[r][c + 1] = v.y;
        tile[r][c + 2] = v.z; tile[r][c + 3] = v.w;
    }
    __syncthreads();
    #pragma unroll
    for (int i = 0; i < 4; i++) {
        int e = t + i * 256;
        int n = e >> 4;
        int c = (e & 15) * 4;            // k within tile
        short4 s;
        s.x = f2bf(tile[c + 0][n]); s.y = f2bf(tile[c + 1][n]);
        s.z = f2bf(tile[c + 2][n]); s.w = f2bf(tile[c + 3][n]);
        *(short4*)(Wt + (size_t)(n0 + n) * K + k0 + c) = s;
    }
}

// emb [V][C] fp32 -> emb16 [VPAD][C] bf16 (pad rows zero)
__global__ __launch_bounds__(256) void embconv(const float* __restrict__ emb,
                                               ushort_t* __restrict__ emb16) {
    size_t e = ((size_t)blockIdx.x * 256 + threadIdx.x) * 4;   // grid: VPAD*C_/1024
    int row = (int)(e / C_);
    short4 s = {0, 0, 0, 0};
    if (row < V_) {
        float4 v = *(const float4*)(emb + e);
        s.x = f2bf(v.x); s.y = f2bf(v.y); s.z = f2bf(v.z); s.w = f2bf(v.w);
    }
    *(short4*)(emb16 + e) = s;
}

// ------------------------------------------------------------- layernorm ---
// fp32 in, bf16 out (all LN consumers are GEMM A-operands)
__global__ __launch_bounds__(256) void ln_k(const float* __restrict__ x,
                                            const float* __restrict__ w,
                                            const float* __restrict__ b,
                                            ushort_t* __restrict__ y) {
    int row = blockIdx.x;
    int tid = threadIdx.x;
    int lane = tid & 63, wv = tid >> 6;
    const float* xr = x + (size_t)row * C_;
    float v0 = xr[tid], v1 = xr[tid + 256], v2 = xr[tid + 512];
    float s = v0 + v1 + v2;
    #pragma unroll
    for (int off = 32; off; off >>= 1) s += __shfl_xor(s, off);
    __shared__ float wr[4];
    __shared__ float wr2[4];
    if (lane == 0) wr[wv] = s;
    __syncthreads();
    float mean = (wr[0] + wr[1] + wr[2] + wr[3]) * (1.0f / 768.0f);
    float d0 = v0 - mean, d1 = v1 - mean, d2 = v2 - mean;
    float sq = d0 * d0 + d1 * d1 + d2 * d2;
    #pragma unroll
    for (int off = 32; off; off >>= 1) sq += __shfl_xor(sq, off);
    if (lane == 0) wr2[wv] = sq;
    __syncthreads();
    float var = (wr2[0] + wr2[1] + wr2[2] + wr2[3]) * (1.0f / 768.0f);
    float rstd = rsqrtf(var + 1e-5f);
    ushort_t* yr = y + (size_t)row * C_;
    yr[tid]       = f2bf(d0 * rstd * w[tid]       + b[tid]);
    yr[tid + 256] = f2bf(d1 * rstd * w[tid + 256] + b[tid + 256]);
    yr[tid + 512] = f2bf(d2 * rstd * w[tid + 512] + b[tid + 512]);
}

// ------------------------------------------------------------------ gemm ---
// D[M,N] = A[M,K] @ Bt[N,K]^T, bf16 operands, fp32 accum.
// m97 structure: 128x128 tile, BK=32, global_load_lds(16B) staging, linear LDS.
// EPI: 0 = fp32 store; 1 = +bias, GELU, bf16 store to D16;
//      2 = +resid, fp32 store; 3 = +bias +resid, fp32 store.
template <int EPI>
__global__ __launch_bounds__(256) void gemm_bf(const ushort_t* __restrict__ A,
                                               const ushort_t* __restrict__ Bt,
                                               const float* __restrict__ bias,
                                               const float* __restrict__ resid,
                                               float* __restrict__ D,
                                               ushort_t* __restrict__ D16,
                                               int M, int N, int K) {
    __shared__ ushort_t As[128 * 32];
    __shared__ ushort_t Bs[128 * 32];
    int tid = threadIdx.x;
    int lane = tid & 63, w = tid >> 6;
    int l15 = lane & 15, quad = lane >> 4;
    int wm = w >> 1, wn = w & 1;
    int m0 = blockIdx.y * 128, n0 = blockIdx.x * 128;

    f32x4 acc[4][4];
    #pragma unroll
    for (int i = 0; i < 4; i++)
        #pragma unroll
        for (int j = 0; j < 4; j++)
            acc[i][j] = (f32x4){0.f, 0.f, 0.f, 0.f};

    // staging geometry: each wave stages 32 rows (2 insts x 16 rows) per matrix.
    int sr = lane >> 2;              // row within 16-row group
    int sc = (lane & 3) << 3;        // k element offset (0,8,16,24)
    const ushort_t* Ag = A  + (size_t)(m0 + (w << 5) + sr) * K + sc;
    const ushort_t* Bg = Bt + (size_t)(n0 + (w << 5) + sr) * K + sc;
    ushort_t* Asl = &As[(w << 5) * 32];
    ushort_t* Bsl = &Bs[(w << 5) * 32];

    for (int k0 = 0; k0 < K; k0 += 32) {
        __syncthreads();
        gload16(Ag + k0, Asl);
        gload16(Ag + k0 + (size_t)16 * K, Asl + 16 * 32);
        gload16(Bg + k0, Bsl);
        gload16(Bg + k0 + (size_t)16 * K, Bsl + 16 * 32);
        __syncthreads();   // compiler drains vmcnt before s_barrier
        bf16x8 af[4], bq[4];
        #pragma unroll
        for (int t = 0; t < 4; t++) {
            af[t] = *(const bf16x8*)&As[(wm * 64 + t * 16 + l15) * 32 + quad * 8];
            bq[t] = *(const bf16x8*)&Bs[(wn * 64 + t * 16 + l15) * 32 + quad * 8];
        }
        #pragma unroll
        for (int mt = 0; mt < 4; mt++)
            #pragma unroll
            for (int nt = 0; nt < 4; nt++)
                acc[mt][nt] = __builtin_amdgcn_mfma_f32_16x16x32_bf16(
                    af[mt], bq[nt], acc[mt][nt], 0, 0, 0);
    }

    #pragma unroll
    for (int mt = 0; mt < 4; mt++) {
        int row = m0 + wm * 64 + mt * 16 + quad * 4;
        #pragma unroll
        for (int nt = 0; nt < 4; nt++) {
            int col = n0 + wn * 64 + nt * 16 + l15;
            if (col < N) {
                #pragma unroll
                for (int r = 0; r < 4; r++) {
                    float v = acc[mt][nt][r];
                    int rr = row + r;
                    if (EPI == 1 || EPI == 3) v += bias[col];
                    if (EPI == 1) {
                        v = 0.5f * v * (1.0f + erff(v * 0.70710678118f));
                        D16[(size_t)rr * N + col] = f2bf(v);
                    } else {
                        if (EPI == 2 || EPI == 3) v += resid[(size_t)rr * N + col];
                        D[(size_t)rr * N + col] = v;
                    }
                }
            }
        }
    }
}

// --------------------------------------------------------- flash attention -
// One block per (64-query tile, b*H). 4 waves, each owns 16 query rows.
// qkv fp32 in, att_out bf16 (proj GEMM A-operand).
#define QBLK 64
#define KVBLK 64
#define LDK 72
#define LDP 72

__global__ __launch_bounds__(256) void attn_flash(const float* __restrict__ qkv,
                                                  ushort_t* __restrict__ att_out) {
    int qt = blockIdx.x;
    int bh = blockIdx.y;
    int b = bh / H_, h = bh - b * H_;
    int hoff = h * HD;
    const size_t base = (size_t)b * T_ * C3;
    int tid = threadIdx.x;
    int lane = tid & 63, w = tid >> 6;
    int l15 = lane & 15, quad = lane >> 4;

    __shared__ short Ks[KVBLK * LDK];
    __shared__ short Vs[HD * LDK];       // transposed: [d][j]
    __shared__ short Ps[4][16 * LDP];    // per-wave P re-fragment buffer

    int q0 = qt * QBLK;
    int qrow_w = q0 + w * 16;

    bf16x8 qf[2];
    {
        const float* qp = qkv + base + (size_t)(qrow_w + l15) * C3 + hoff;
        #pragma unroll
        for (int ks = 0; ks < 2; ks++)
            #pragma unroll
            for (int e = 0; e < 8; e++)
                qf[ks][e] = f2bf(qp[ks * 32 + quad * 8 + e] * 0.125f);
    }

    f32x4 o[4];
    #pragma unroll
    for (int nt = 0; nt < 4; nt++) o[nt] = (f32x4){0.f, 0.f, 0.f, 0.f};
    float m_r[4] = {-1e30f, -1e30f, -1e30f, -1e30f};
    float l_r[4] = {0.f, 0.f, 0.f, 0.f};

    for (int j0 = 0; j0 < q0 + QBLK; j0 += KVBLK) {
        __syncthreads();
        #pragma unroll
        for (int i = 0; i < 4; i++) {
            int e4 = tid + i * 256;
            int j = e4 >> 4;
            int dc = (e4 & 15) << 2;
            float4 kv = *(const float4*)(qkv + base + (size_t)(j0 + j) * C3 + C_ + hoff + dc);
            short4 s4 = { f2bf(kv.x), f2bf(kv.y), f2bf(kv.z), f2bf(kv.w) };
            *(short4*)&Ks[j * LDK + dc] = s4;
            int jV = tid & 63;
            int dV = ((tid >> 6) + i * 4) << 2;
            float4 vv = *(const float4*)(qkv + base + (size_t)(j0 + jV) * C3 + 2 * C_ + hoff + dV);
            Vs[(dV + 0) * LDK + jV] = f2bf(vv.x);
            Vs[(dV + 1) * LDK + jV] = f2bf(vv.y);
            Vs[(dV + 2) * LDK + jV] = f2bf(vv.z);
            Vs[(dV + 3) * LDK + jV] = f2bf(vv.w);
        }
        __syncthreads();
        if (j0 > qrow_w + 15) continue;

        f32x4 s[4];
        #pragma unroll
        for (int nt = 0; nt < 4; nt++) s[nt] = (f32x4){0.f, 0.f, 0.f, 0.f};
        #pragma unroll
        for (int ks = 0; ks < 2; ks++)
            #pragma unroll
            for (int nt = 0; nt < 4; nt++) {
                bf16x8 kf = *(const bf16x8*)&Ks[(nt * 16 + l15) * LDK + ks * 32 + quad * 8];
                s[nt] = __builtin_amdgcn_mfma_f32_16x16x32_bf16(qf[ks], kf, s[nt], 0, 0, 0);
            }

        float tmax[4] = {-1e30f, -1e30f, -1e30f, -1e30f};
        #pragma unroll
        for (int nt = 0; nt < 4; nt++) {
            int key = j0 + nt * 16 + l15;
            #pragma unroll
            for (int r = 0; r < 4; r++) {
                int row = qrow_w + quad * 4 + r;
                if (key > row) s[nt][r] = -1e30f;
                tmax[r] = fmaxf(tmax[r], s[nt][r]);
            }
        }
        float rsum[4];
        #pragma unroll
        for (int r = 0; r < 4; r++) {
            #pragma unroll
            for (int off = 1; off < 16; off <<= 1)
                tmax[r] = fmaxf(tmax[r], __shfl_xor(tmax[r], off));
            float mnew = fmaxf(m_r[r], tmax[r]);
            float sc = __expf(m_r[r] - mnew);
            m_r[r] = mnew;
            l_r[r] *= sc;
            #pragma unroll
            for (int nt = 0; nt < 4; nt++) o[nt][r] *= sc;
            rsum[r] = 0.f;
        }

        #pragma unroll
        for (int nt = 0; nt < 4; nt++)
            #pragma unroll
            for (int r = 0; r < 4; r++) {
                float p = __expf(s[nt][r] - m_r[r]);
                rsum[r] += p;
                Ps[w][(quad * 4 + r) * LDP + nt * 16 + l15] = f2bf(p);
            }
        #pragma unroll
        for (int r = 0; r < 4; r++) {
            #pragma unroll
            for (int off = 1; off < 16; off <<= 1)
                rsum[r] += __shfl_xor(rsum[r], off);
            l_r[r] += rsum[r];
        }
        asm volatile("s_waitcnt lgkmcnt(0)" ::: "memory");

        #pragma unroll
        for (int ks = 0; ks < 2; ks++) {
            bf16x8 pf = *(const bf16x8*)&Ps[w][l15 * LDP + ks * 32 + quad * 8];
            #pragma unroll
            for (int nt = 0; nt < 4; nt++) {
                bf16x8 vf = *(const bf16x8*)&Vs[(nt * 16 + l15) * LDK + ks * 32 + quad * 8];
                o[nt] = __builtin_amdgcn_mfma_f32_16x16x32_bf16(pf, vf, o[nt], 0, 0, 0);
            }
        }
    }

    #pragma unroll
    for (int r = 0; r < 4; r++) {
        int row = qrow_w + quad * 4 + r;
        float inv = 1.0f / l_r[r];
        #pragma unroll
        for (int nt = 0; nt < 4; nt++)
            att_out[((size_t)b * T_ + row) * C_ + hoff + nt * 16 + l15] =
                f2bf(o[nt][r] * inv);
    }
}

// ---------------------------------------------------------------- launch ---
extern "C" void kernel_launch(void* const* d_in, const int* in_sizes, int n_in,
                              void* d_out, int out_size, void* d_ws, size_t ws_size,
                              hipStream_t stream) {
    const int*   idx   = (const int*)d_in[0];
    const float* emb   = (const float*)d_in[1];
    const float* pos   = (const float*)d_in[2];
    const float* Wqkv  = (const float*)d_in[3];
    const float* Wproj = (const float*)d_in[4];
    const float* ln1w  = (const float*)d_in[5];
    const float* ln1b  = (const float*)d_in[6];
    const float* ln2w  = (const float*)d_in[7];
    const float* ln2b  = (const float*)d_in[8];
    const float* W1    = (const float*)d_in[9];
    const float* b1    = (const float*)d_in[10];
    const float* W2    = (const float*)d_in[11];
    const float* b2    = (const float*)d_in[12];
    const float* lnfw  = (const float*)d_in[13];
    const float* lnfb  = (const float*)d_in[14];
    float* out = (float*)d_out;

    // fp32 region
    float* ws   = (float*)d_ws;
    float* x    = ws;                              // BT*C f32
    float* qkv  = x + (size_t)BT * C_;             // BT*3C f32
    // bf16 region
    ushort_t* lnb16  = (ushort_t*)(qkv + (size_t)BT * C3);   // BT*C
    ushort_t* att16  = lnb16 + (size_t)BT * C_;              // BT*C
    ushort_t* hbuf16 = att16 + (size_t)BT * C_;              // BT*4C
    ushort_t* wq_t   = hbuf16 + (size_t)BT * C4;             // L*C3*C  ([n][k])
    ushort_t* wp_t   = wq_t + (size_t)L_ * C3 * C_;          // L*C*C
    ushort_t* w1_t   = wp_t + (size_t)L_ * C_ * C_;          // L*C4*C
    ushort_t* w2_t   = w1_t + (size_t)L_ * C_ * C4;          // L*C*C4
    ushort_t* emb16  = w2_t + (size_t)L_ * C4 * C_;          // VPAD*C

    // ---- one-time weight prep (idempotent, stream-ordered) ----
    wconv_t<<<dim3(C3 / 64, C_ / 64, L_), 256, 0, stream>>>(Wqkv, wq_t, C_, C3);
    wconv_t<<<dim3(C_ / 64, C_ / 64, L_), 256, 0, stream>>>(Wproj, wp_t, C_, C_);
    wconv_t<<<dim3(C4 / 64, C_ / 64, L_), 256, 0, stream>>>(W1, w1_t, C_, C4);
    wconv_t<<<dim3(C_ / 64, C4 / 64, L_), 256, 0, stream>>>(W2, w2_t, C4, C_);
    embconv<<<(VPAD * C_) / 1024, 256, 0, stream>>>(emb, emb16);

    embed_k<<<(BT * C_) / 256, 256, 0, stream>>>(idx, emb, pos, x);

    for (int l = 0; l < L_; l++) {
        ln_k<<<BT, 256, 0, stream>>>(x, ln1w + (size_t)l * C_, ln1b + (size_t)l * C_, lnb16);
        gemm_bf<0><<<dim3(C3 / 128, BT / 128), 256, 0, stream>>>(
            lnb16, wq_t + (size_t)l * C3 * C_, nullptr, nullptr, qkv, nullptr, BT, C3, C_);
        attn_flash<<<dim3(T_ / QBLK, B_ * H_), 256, 0, stream>>>(qkv, att16);
        gemm_bf<2><<<dim3(C_ / 128, BT / 128), 256, 0, stream>>>(
            att16, wp_t + (size_t)l * C_ * C_, nullptr, x, x, nullptr, BT, C_, C_);
        ln_k<<<BT, 256, 0, stream>>>(x, ln2w + (size_t)l * C_, ln2b + (size_t)l * C_, lnb16);
        gemm_bf<1><<<dim3(C4 / 128, BT / 128), 256, 0, stream>>>(
            lnb16, w1_t + (size_t)l * C4 * C_, b1 + (size_t)l * C4, nullptr, nullptr, hbuf16, BT, C4, C_);
        gemm_bf<3><<<dim3(C_ / 128, BT / 128), 256, 0, stream>>>(
            hbuf16, w2_t + (size_t)l * C_ * C4, b2 + (size_t)l * C_, x, x, nullptr, BT, C_, C4);
    }

    ln_k<<<BT, 256, 0, stream>>>(x, lnfw, lnfb, lnb16);
    // logits = lnb @ emb16^T (emb16 is [VPAD][C] bf16, pad rows unused via col<N guard)
    gemm_bf<0><<<dim3(VPAD / 128, BT / 128), 256, 0, stream>>>(
        lnb16, emb16, nullptr, nullptr, out, nullptr, BT, V_, C_);
}